// Round 11
// baseline (223.183 us; speedup 1.0000x reference)
//
#include <hip/hip_runtime.h>

#define B_ 16
#define C_ 256
#define N_ 16384      // 128*128
#define R_ 16
#define BPB_ 16       // blocks per batch in kA (grid 16 x 16 = 256 = 1/CU)

typedef float f32x4 __attribute__((ext_vector_type(4)));

__device__ __forceinline__ float4 ldf4(const float* p) {
    return *reinterpret_cast<const float4*>(p);
}

// ---------------------------------------------------------------------------
// kA: fused stats pass, LINEAR wave segments (the fix for the 3.3 TB/s kA).
// 1024 thr = 16 waves; wave w owns channels 16w..16w+15; lane l owns the
// float4 at n = n0+4l of each row -> every global load is one contiguous
// 1-KiB wave segment (1 DRAM page), vs the 8x128B scatter of R4/R8/R10.
// Per 256-n phase: 16 linear loads into rows[16] (regs), lane-local colsum
// partial (no shuffles), 1 f4 LDS write/wave, sync, sum 16 wave partials,
// sync, then accP[r] += rows[r].cl, accRS[r] += sum4(rows[r]).
// End of block: 6-step butterfly per row folds the 64 lanes.
// ---------------------------------------------------------------------------
__global__ __launch_bounds__(1024, 4)
void kA(const float* __restrict__ x,
        float* __restrict__ Ppart,
        float* __restrict__ RSpart) {
    const int blk = blockIdx.x;     // n-chunk (1024 n)
    const int b = blockIdx.y;
    const int t = threadIdx.x;
    const int lane = t & 63;
    const int w = t >> 6;           // wave 0..15

    __shared__ float4 csp[16][64];  // per-wave colsum partials

    // wave w, row r -> channel c = 16w + r; lane's n offset = 4*lane
    const float* xw = x + ((size_t)(b * C_ + (w << 4))) * N_
                    + blk * 1024 + (lane << 2);

    float accP[16], accRS[16];
#pragma unroll
    for (int r = 0; r < 16; ++r) { accP[r] = 0.f; accRS[r] = 0.f; }

#pragma unroll
    for (int ph = 0; ph < 4; ++ph) {
        const int noff = ph * 256;
        float4 rows[16];
#pragma unroll
        for (int r = 0; r < 16; ++r)
            rows[r] = ldf4(xw + (size_t)r * N_ + noff);

        // lane-local colsum partial over this wave's 16 channels
        float4 cs = rows[0];
#pragma unroll
        for (int r = 1; r < 16; ++r) {
            cs.x += rows[r].x; cs.y += rows[r].y;
            cs.z += rows[r].z; cs.w += rows[r].w;
        }
        csp[w][lane] = cs;
        __syncthreads();

        // full colsum for this lane's 4 n's: sum the 16 wave partials
        float4 cl = csp[0][lane];
#pragma unroll
        for (int w2 = 1; w2 < 16; ++w2) {
            float4 p = csp[w2][lane];
            cl.x += p.x; cl.y += p.y; cl.z += p.z; cl.w += p.w;
        }
        __syncthreads();   // csp reusable next phase

        // P / RS accumulation straight from registers
#pragma unroll
        for (int r = 0; r < 16; ++r) {
            accP[r] += rows[r].x * cl.x + rows[r].y * cl.y
                     + rows[r].z * cl.z + rows[r].w * cl.w;
            accRS[r] += (rows[r].x + rows[r].y) + (rows[r].z + rows[r].w);
        }
    }

    // fold 64 lanes per row (butterfly), write per-channel block partials
#pragma unroll
    for (int r = 0; r < 16; ++r) {
#pragma unroll
        for (int m = 1; m <= 32; m <<= 1) {
            accP[r]  += __shfl_xor(accP[r],  m, 64);
            accRS[r] += __shfl_xor(accRS[r], m, 64);
        }
    }
    if (lane == 0) {
        const size_t base = ((size_t)b * BPB_ + blk) * C_ + (w << 4);
#pragma unroll
        for (int r = 0; r < 16; ++r) {
            Ppart [base + r] = accP[r];
            RSpart[base + r] = accRS[r];
        }
    }
}

// ---------------------------------------------------------------------------
// kB: reduce partials -> v -> fused MLP -> gate.  grid(B_) x 256, thread = c.
// ---------------------------------------------------------------------------
__global__ void kB(const float* __restrict__ Ppart,
                   const float* __restrict__ RSpart,
                   const float* __restrict__ w1, const float* __restrict__ b1,
                   const float* __restrict__ w2, const float* __restrict__ b2,
                   float* __restrict__ gate) {
    const int b = blockIdx.x;
    const int t = threadIdx.x;   // channel c

    float P = 0.f, RS = 0.f;
#pragma unroll
    for (int k = 0; k < BPB_; ++k) {
        P  += Ppart [((size_t)b * BPB_ + k) * C_ + t];
        RS += RSpart[((size_t)b * BPB_ + k) * C_ + t];
    }

    __shared__ float red[4];
    float s = RS;
#pragma unroll
    for (int off = 32; off; off >>= 1) s += __shfl_down(s, off, 64);
    if ((t & 63) == 0) red[t >> 6] = s;
    __syncthreads();
    const float T = red[0] + red[1] + red[2] + red[3];
    const float M = T / (float)N_;
    const float denom = (float)(N_ - 1) * (float)C_;

    __shared__ float vl[C_];
    vl[t] = (P - M * RS) / denom;
    __syncthreads();

    __shared__ float hpart[R_][16];
    __shared__ float h1[R_];
    {
        const int i = t >> 4, cc = t & 15;
        float a = 0.f;
#pragma unroll
        for (int k = 0; k < 16; ++k)
            a += vl[(cc << 4) + k] * w1[i * C_ + (cc << 4) + k];
        hpart[i][cc] = a;
    }
    __syncthreads();
    if (t < R_) {
        float a = b1[t];
#pragma unroll
        for (int k = 0; k < 16; ++k) a += hpart[t][k];
        h1[t] = a > 0.f ? a : 0.f;
    }
    __syncthreads();

    float a = b2[t];
#pragma unroll
    for (int i = 0; i < R_; ++i) a += h1[i] * w2[t * R_ + i];
    gate[b * C_ + t] = 1.f / (1.f + __expf(-a));
}

// ---------------------------------------------------------------------------
// kC: out = x * gate[b,c]; non-temporal stores (proven).
// ---------------------------------------------------------------------------
__global__ void kC(const float* __restrict__ x,
                   const float* __restrict__ gate,
                   float* __restrict__ out) {
    const size_t total4 = (size_t)B_ * C_ * N_ / 4;
    for (size_t i = (size_t)blockIdx.x * blockDim.x + threadIdx.x; i < total4;
         i += (size_t)gridDim.x * blockDim.x) {
        const int bc = (int)(i >> 12);           // N_/4 = 4096 float4 per (b,c)
        const float g = gate[bc];
        float4 vx = reinterpret_cast<const float4*>(x)[i];
        f32x4 r;
        r.x = vx.x * g; r.y = vx.y * g; r.z = vx.z * g; r.w = vx.w * g;
        __builtin_nontemporal_store(r, reinterpret_cast<f32x4*>(out) + i);
    }
}

extern "C" void kernel_launch(void* const* d_in, const int* in_sizes, int n_in,
                              void* d_out, int out_size, void* d_ws, size_t ws_size,
                              hipStream_t stream) {
    (void)in_sizes; (void)n_in; (void)out_size; (void)ws_size;
    const float* x  = (const float*)d_in[0];
    const float* w1 = (const float*)d_in[1];
    const float* b1 = (const float*)d_in[2];
    const float* w2 = (const float*)d_in[3];
    const float* b2 = (const float*)d_in[4];
    float* out = (float*)d_out;

    float* ws     = (float*)d_ws;
    float* Ppart  = ws;                                    // B_*BPB_*C_ = 65536
    float* RSpart = Ppart + (size_t)B_ * BPB_ * C_;        // 65536
    float* gate   = RSpart + (size_t)B_ * BPB_ * C_;       // B_*C_

    hipLaunchKernelGGL(kA, dim3(BPB_, B_), dim3(1024), 0, stream,
                       x, Ppart, RSpart);
    hipLaunchKernelGGL(kB, dim3(B_), dim3(256), 0, stream,
                       Ppart, RSpart, w1, b1, w2, b2, gate);
    hipLaunchKernelGGL(kC, dim3(2048), dim3(256), 0, stream,
                       x, gate, out);
}

// Round 12
// 184.970 us; speedup vs baseline: 1.2066x; 1.2066x over previous
//
#include <hip/hip_runtime.h>

#define B_ 16
#define C_ 256
#define N_ 16384      // 128*128
#define R_ 16
#define BPB_ 16       // blocks per batch in kA (grid 16 x 16 = 256 = 1/CU)

typedef float f32x4 __attribute__((ext_vector_type(4)));

__device__ __forceinline__ float4 ldf4(const float* p) {
    return *reinterpret_cast<const float4*>(p);
}
__device__ __forceinline__ unsigned f2bf(float f) {     // round-half-up bf16
    return (__float_as_uint(f) + 0x8000u) >> 16;
}

// ---------------------------------------------------------------------------
// kA: fused stats pass, LINEAR 1-KiB wave segments, bf16 row retention.
// 1024 thr = 16 waves; wave w owns channels 16w..16w+15; lane l owns the
// float4 at n = n0+4l -> every global load is one contiguous 1-KiB wave
// segment (R11 plan).  R11's spill bug fixed: rows retained as bf16 packed
// in uint2 (32 VGPR, not 64); colsum & RS accumulated from the EXACT fp32
// values at load time; only the P-dot uses the bf16 copy (error ~1e-5 on a
// 5.4e-2 threshold).  No LDS tile; 16 KiB colsum-exchange only.
// ---------------------------------------------------------------------------
__global__ __launch_bounds__(1024)
void kA(const float* __restrict__ x,
        float* __restrict__ Ppart,
        float* __restrict__ RSpart) {
    const int blk = blockIdx.x;     // n-chunk (1024 n)
    const int b = blockIdx.y;
    const int t = threadIdx.x;
    const int lane = t & 63;
    const int w = t >> 6;           // wave 0..15

    __shared__ float4 csp[16][64];  // per-wave colsum partials

    const float* xw = x + ((size_t)(b * C_ + (w << 4))) * N_
                    + blk * 1024 + (lane << 2);

    float accP[16], accRS[16];
#pragma unroll
    for (int r = 0; r < 16; ++r) { accP[r] = 0.f; accRS[r] = 0.f; }

    for (int ph = 0; ph < 4; ++ph) {
        const int noff = ph * 256;
        uint2 rb[16];                       // bf16x4 retained rows (32 VGPR)
        float4 csl = make_float4(0.f, 0.f, 0.f, 0.f);
#pragma unroll
        for (int r = 0; r < 16; ++r) {
            float4 v = ldf4(xw + (size_t)r * N_ + noff);
            csl.x += v.x; csl.y += v.y; csl.z += v.z; csl.w += v.w;
            accRS[r] += (v.x + v.y) + (v.z + v.w);
            rb[r].x = f2bf(v.x) | (f2bf(v.y) << 16);
            rb[r].y = f2bf(v.z) | (f2bf(v.w) << 16);
        }
        csp[w][lane] = csl;
        __syncthreads();
        float4 cl = csp[0][lane];
#pragma unroll
        for (int w2 = 1; w2 < 16; ++w2) {
            float4 p = csp[w2][lane];
            cl.x += p.x; cl.y += p.y; cl.z += p.z; cl.w += p.w;
        }
        __syncthreads();                    // csp reusable next phase
#pragma unroll
        for (int r = 0; r < 16; ++r) {
            const float vx = __uint_as_float(rb[r].x << 16);
            const float vy = __uint_as_float(rb[r].x & 0xFFFF0000u);
            const float vz = __uint_as_float(rb[r].y << 16);
            const float vw = __uint_as_float(rb[r].y & 0xFFFF0000u);
            accP[r] += vx * cl.x + vy * cl.y + vz * cl.z + vw * cl.w;
        }
    }

    // fold 64 lanes per row (butterfly), write per-channel block partials
#pragma unroll
    for (int r = 0; r < 16; ++r) {
#pragma unroll
        for (int m = 1; m <= 32; m <<= 1) {
            accP[r]  += __shfl_xor(accP[r],  m, 64);
            accRS[r] += __shfl_xor(accRS[r], m, 64);
        }
    }
    if (lane == 0) {
        const size_t base = ((size_t)b * BPB_ + blk) * C_ + (w << 4);
#pragma unroll
        for (int r = 0; r < 16; ++r) {
            Ppart [base + r] = accP[r];
            RSpart[base + r] = accRS[r];
        }
    }
}

// ---------------------------------------------------------------------------
// kB: reduce partials -> v -> fused MLP -> gate.  grid(B_) x 256, thread = c.
// ---------------------------------------------------------------------------
__global__ void kB(const float* __restrict__ Ppart,
                   const float* __restrict__ RSpart,
                   const float* __restrict__ w1, const float* __restrict__ b1,
                   const float* __restrict__ w2, const float* __restrict__ b2,
                   float* __restrict__ gate) {
    const int b = blockIdx.x;
    const int t = threadIdx.x;   // channel c

    float P = 0.f, RS = 0.f;
#pragma unroll
    for (int k = 0; k < BPB_; ++k) {
        P  += Ppart [((size_t)b * BPB_ + k) * C_ + t];
        RS += RSpart[((size_t)b * BPB_ + k) * C_ + t];
    }

    __shared__ float red[4];
    float s = RS;
#pragma unroll
    for (int off = 32; off; off >>= 1) s += __shfl_down(s, off, 64);
    if ((t & 63) == 0) red[t >> 6] = s;
    __syncthreads();
    const float T = red[0] + red[1] + red[2] + red[3];
    const float M = T / (float)N_;
    const float denom = (float)(N_ - 1) * (float)C_;

    __shared__ float vl[C_];
    vl[t] = (P - M * RS) / denom;
    __syncthreads();

    __shared__ float hpart[R_][16];
    __shared__ float h1[R_];
    {
        const int i = t >> 4, cc = t & 15;
        float a = 0.f;
#pragma unroll
        for (int k = 0; k < 16; ++k)
            a += vl[(cc << 4) + k] * w1[i * C_ + (cc << 4) + k];
        hpart[i][cc] = a;
    }
    __syncthreads();
    if (t < R_) {
        float a = b1[t];
#pragma unroll
        for (int k = 0; k < 16; ++k) a += hpart[t][k];
        h1[t] = a > 0.f ? a : 0.f;
    }
    __syncthreads();

    float a = b2[t];
#pragma unroll
    for (int i = 0; i < R_; ++i) a += h1[i] * w2[t * R_ + i];
    gate[b * C_ + t] = 1.f / (1.f + __expf(-a));
}

// ---------------------------------------------------------------------------
// kC: out = x * gate[b,c]; non-temporal stores (proven).
// ---------------------------------------------------------------------------
__global__ void kC(const float* __restrict__ x,
                   const float* __restrict__ gate,
                   float* __restrict__ out) {
    const size_t total4 = (size_t)B_ * C_ * N_ / 4;
    for (size_t i = (size_t)blockIdx.x * blockDim.x + threadIdx.x; i < total4;
         i += (size_t)gridDim.x * blockDim.x) {
        const int bc = (int)(i >> 12);           // N_/4 = 4096 float4 per (b,c)
        const float g = gate[bc];
        float4 vx = reinterpret_cast<const float4*>(x)[i];
        f32x4 r;
        r.x = vx.x * g; r.y = vx.y * g; r.z = vx.z * g; r.w = vx.w * g;
        __builtin_nontemporal_store(r, reinterpret_cast<f32x4*>(out) + i);
    }
}

extern "C" void kernel_launch(void* const* d_in, const int* in_sizes, int n_in,
                              void* d_out, int out_size, void* d_ws, size_t ws_size,
                              hipStream_t stream) {
    (void)in_sizes; (void)n_in; (void)out_size; (void)ws_size;
    const float* x  = (const float*)d_in[0];
    const float* w1 = (const float*)d_in[1];
    const float* b1 = (const float*)d_in[2];
    const float* w2 = (const float*)d_in[3];
    const float* b2 = (const float*)d_in[4];
    float* out = (float*)d_out;

    float* ws     = (float*)d_ws;
    float* Ppart  = ws;                                    // B_*BPB_*C_ = 65536
    float* RSpart = Ppart + (size_t)B_ * BPB_ * C_;        // 65536
    float* gate   = RSpart + (size_t)B_ * BPB_ * C_;       // B_*C_

    hipLaunchKernelGGL(kA, dim3(BPB_, B_), dim3(1024), 0, stream,
                       x, Ppart, RSpart);
    hipLaunchKernelGGL(kB, dim3(B_), dim3(256), 0, stream,
                       Ppart, RSpart, w1, b1, w2, b2, gate);
    hipLaunchKernelGGL(kC, dim3(2048), dim3(256), 0, stream,
                       x, gate, out);
}

// Round 13
// 143.599 us; speedup vs baseline: 1.5542x; 1.2881x over previous
//
#include <hip/hip_runtime.h>

#define B_ 16
#define C_ 256
#define N_ 16384      // 128*128
#define R_ 16
#define W_ 128        // n per kA tile
#define TPB_ 128      // tiles per batch = N_/W_
#define R16_ 16

typedef float f32x4 __attribute__((ext_vector_type(4)));

__device__ __forceinline__ float4 ldf4(const float* p) {
    return *reinterpret_cast<const float4*>(p);
}
__device__ __forceinline__ unsigned f2bf(float f) {     // round-half-up bf16
    return (__float_as_uint(f) + 0x8000u) >> 16;
}

// ---------------------------------------------------------------------------
// kA: streaming phase A (k1-style, barrier-free) + bf16 LDS retention.
// Block (512 thr, 8 waves) owns tile = x[b, 0:256, n0:n0+128].
// Phase A: wave w streams rows c=32w..32w+31, one float2/lane (512 B
// contiguous wave segments), colsum in a single f2 reg (no cross-lane work),
// values parked as bf16 in tl[256][130] (row stride 65 dwords -> all banks
// (c+k)%32, 2-way max).  NO barriers in the loop.
// Phase B: one barrier, colsum combine, barrier; thread t dots row (t&255),
// half (t>>8) against colsum; pair-combine via LDS; write P/RS partials.
// LDS ~72 KiB -> 2 blocks/CU: phase A of one block overlaps phase B of the
// other.  P/RS from bf16 copy (validated R12: absmax unchanged).
// ---------------------------------------------------------------------------
__global__ __launch_bounds__(512)
void kA(const float* __restrict__ x,
        float* __restrict__ Ppart,
        float* __restrict__ RSpart) {
    const int tile = blockIdx.x;    // 0..127
    const int b = blockIdx.y;
    const int t = threadIdx.x;      // 0..511
    const int lane = t & 63;
    const int w = t >> 6;           // wave 0..7

    __shared__ ushort tl[C_][130];      // bf16 tile, 65-dword row stride
    __shared__ float csp[8][64][2];     // per-wave colsum partials
    __shared__ float colsum[W_];
    __shared__ float phalf[C_][2];      // phase-B half-row exchange

    const float* xt = x + (size_t)b * C_ * N_ + tile * W_ + (lane << 1);

    // ---- phase A: barrier-free streaming of 32 rows per wave
    float2 cs = make_float2(0.f, 0.f);
    const int c0 = w << 5;
#pragma unroll 8
    for (int k = 0; k < 32; ++k) {
        const int c = c0 + k;
        float2 v = *reinterpret_cast<const float2*>(xt + (size_t)c * N_);
        cs.x += v.x; cs.y += v.y;
        *reinterpret_cast<unsigned*>(&tl[c][lane << 1]) =
            f2bf(v.x) | (f2bf(v.y) << 16);
    }
    csp[w][lane][0] = cs.x;
    csp[w][lane][1] = cs.y;
    __syncthreads();

    if (t < W_) {       // colsum[n]: sum the 8 wave partials (lane n>>1, comp n&1)
        float s = 0.f;
#pragma unroll
        for (int ww = 0; ww < 8; ++ww) s += csp[ww][t >> 1][t & 1];
        colsum[t] = s;
    }
    __syncthreads();

    // ---- phase B: thread t owns (c = t&255, half h = t>>8)
    const int c = t & 255, h = t >> 8;
    const unsigned* row = reinterpret_cast<const unsigned*>(&tl[c][0]) + (h << 5);
    const float* csh = colsum + (h << 6);
    float P = 0.f, RS = 0.f;
#pragma unroll
    for (int k = 0; k < 32; ++k) {
        const unsigned pk = row[k];
        const float vx = __uint_as_float(pk << 16);
        const float vy = __uint_as_float(pk & 0xFFFF0000u);
        P += vx * csh[2 * k] + vy * csh[2 * k + 1];
        RS += vx + vy;
    }
    if (h == 1) { phalf[c][0] = P; phalf[c][1] = RS; }
    __syncthreads();
    if (t < C_) {
        P += phalf[t][0];
        RS += phalf[t][1];
        const size_t base = ((size_t)b * TPB_ + tile) * C_;
        Ppart [base + t] = P;
        RSpart[base + t] = RS;
    }
}

// ---------------------------------------------------------------------------
// kB: reduce 128 partials -> v -> fused MLP -> gate.  grid(B_) x 256.
// ---------------------------------------------------------------------------
__global__ void kB(const float* __restrict__ Ppart,
                   const float* __restrict__ RSpart,
                   const float* __restrict__ w1, const float* __restrict__ b1,
                   const float* __restrict__ w2, const float* __restrict__ b2,
                   float* __restrict__ gate) {
    const int b = blockIdx.x;
    const int t = threadIdx.x;   // channel c

    float P = 0.f, RS = 0.f;
#pragma unroll 8
    for (int k = 0; k < TPB_; ++k) {
        P  += Ppart [((size_t)b * TPB_ + k) * C_ + t];
        RS += RSpart[((size_t)b * TPB_ + k) * C_ + t];
    }

    __shared__ float red[4];
    float s = RS;
#pragma unroll
    for (int off = 32; off; off >>= 1) s += __shfl_down(s, off, 64);
    if ((t & 63) == 0) red[t >> 6] = s;
    __syncthreads();
    const float T = red[0] + red[1] + red[2] + red[3];
    const float M = T / (float)N_;
    const float denom = (float)(N_ - 1) * (float)C_;

    __shared__ float vl[C_];
    vl[t] = (P - M * RS) / denom;
    __syncthreads();

    __shared__ float hpart[R16_][16];
    __shared__ float h1[R16_];
    {
        const int i = t >> 4, cc = t & 15;
        float a = 0.f;
#pragma unroll
        for (int k = 0; k < 16; ++k)
            a += vl[(cc << 4) + k] * w1[i * C_ + (cc << 4) + k];
        hpart[i][cc] = a;
    }
    __syncthreads();
    if (t < R16_) {
        float a = b1[t];
#pragma unroll
        for (int k = 0; k < 16; ++k) a += hpart[t][k];
        h1[t] = a > 0.f ? a : 0.f;
    }
    __syncthreads();

    float a = b2[t];
#pragma unroll
    for (int i = 0; i < R16_; ++i) a += h1[i] * w2[t * R16_ + i];
    gate[b * C_ + t] = 1.f / (1.f + __expf(-a));
}

// ---------------------------------------------------------------------------
// kC: out = x * gate[b,c]; non-temporal stores (proven).
// ---------------------------------------------------------------------------
__global__ void kC(const float* __restrict__ x,
                   const float* __restrict__ gate,
                   float* __restrict__ out) {
    const size_t total4 = (size_t)B_ * C_ * N_ / 4;
    for (size_t i = (size_t)blockIdx.x * blockDim.x + threadIdx.x; i < total4;
         i += (size_t)gridDim.x * blockDim.x) {
        const int bc = (int)(i >> 12);           // N_/4 = 4096 float4 per (b,c)
        const float g = gate[bc];
        float4 vx = reinterpret_cast<const float4*>(x)[i];
        f32x4 r;
        r.x = vx.x * g; r.y = vx.y * g; r.z = vx.z * g; r.w = vx.w * g;
        __builtin_nontemporal_store(r, reinterpret_cast<f32x4*>(out) + i);
    }
}

extern "C" void kernel_launch(void* const* d_in, const int* in_sizes, int n_in,
                              void* d_out, int out_size, void* d_ws, size_t ws_size,
                              hipStream_t stream) {
    (void)in_sizes; (void)n_in; (void)out_size; (void)ws_size;
    const float* x  = (const float*)d_in[0];
    const float* w1 = (const float*)d_in[1];
    const float* b1 = (const float*)d_in[2];
    const float* w2 = (const float*)d_in[3];
    const float* b2 = (const float*)d_in[4];
    float* out = (float*)d_out;

    float* ws     = (float*)d_ws;
    float* Ppart  = ws;                                    // B_*TPB_*C_ = 524288
    float* RSpart = Ppart + (size_t)B_ * TPB_ * C_;        // 524288
    float* gate   = RSpart + (size_t)B_ * TPB_ * C_;       // B_*C_

    hipLaunchKernelGGL(kA, dim3(TPB_, B_), dim3(512), 0, stream,
                       x, Ppart, RSpart);
    hipLaunchKernelGGL(kB, dim3(B_), dim3(256), 0, stream,
                       Ppart, RSpart, w1, b1, w2, b2, gate);
    hipLaunchKernelGGL(kC, dim3(2048), dim3(256), 0, stream,
                       x, gate, out);
}

// Round 14
// 140.116 us; speedup vs baseline: 1.5928x; 1.0249x over previous
//
#include <hip/hip_runtime.h>
#include <hip/hip_bf16.h>

#define B_ 16
#define C_ 256
#define N_ 16384      // 128*128
#define W_ 128        // n per kA tile
#define TPB_ 128      // tiles per batch = N_/W_
#define R16_ 16

typedef float f32x4 __attribute__((ext_vector_type(4)));

__device__ __forceinline__ float bfl(unsigned p) {  // low bf16 -> f32
    return __uint_as_float(p << 16);
}
__device__ __forceinline__ float bfh(unsigned p) {  // high bf16 -> f32
    return __uint_as_float(p & 0xFFFF0000u);
}

// ---------------------------------------------------------------------------
// kA: streaming phase A (barrier-free) + bf16 LDS retention (R13-proven).
// Phase A: wave w streams rows c=32w..32w+31, float2/lane (512 B contiguous
// wave segments), colsum in regs, values packed bf16x2 (v_cvt_pk) into
// tl[256][130].  Phase B: thread t dots row (t&255) half (t>>8) against
// colsum (float4 broadcast reads).  LDS ~71 KiB -> 2 blocks/CU.
// ---------------------------------------------------------------------------
__global__ __launch_bounds__(512)
void kA(const float* __restrict__ x,
        float* __restrict__ Ppart,
        float* __restrict__ RSpart) {
    const int tile = blockIdx.x;    // 0..127
    const int b = blockIdx.y;
    const int t = threadIdx.x;      // 0..511
    const int lane = t & 63;
    const int w = t >> 6;           // wave 0..7

    __shared__ ushort tl[C_][130];      // bf16 tile, 65-dword row stride
    __shared__ float csp[8][64][2];     // per-wave colsum partials
    __shared__ float colsum[W_];
    __shared__ float phalf[C_][2];      // phase-B half-row exchange

    const float* xt = x + (size_t)b * C_ * N_ + tile * W_ + (lane << 1);

    // ---- phase A: barrier-free streaming of 32 rows per wave
    float2 cs = make_float2(0.f, 0.f);
    const int c0 = w << 5;
#pragma unroll 8
    for (int k = 0; k < 32; ++k) {
        const int c = c0 + k;
        float2 v = *reinterpret_cast<const float2*>(xt + (size_t)c * N_);
        cs.x += v.x; cs.y += v.y;
        *reinterpret_cast<__hip_bfloat162*>(&tl[c][lane << 1]) =
            __float22bfloat162_rn(v);
    }
    csp[w][lane][0] = cs.x;
    csp[w][lane][1] = cs.y;
    __syncthreads();

    if (t < W_) {       // colsum[n]: sum the 8 wave partials
        float s = 0.f;
#pragma unroll
        for (int ww = 0; ww < 8; ++ww) s += csp[ww][t >> 1][t & 1];
        colsum[t] = s;
    }
    __syncthreads();

    // ---- phase B: thread t owns (c = t&255, half h = t>>8)
    const int c = t & 255, h = t >> 8;
    const unsigned* row = reinterpret_cast<const unsigned*>(&tl[c][0]) + (h << 5);
    const float4* cs4 = reinterpret_cast<const float4*>(colsum + (h << 6));
    float P = 0.f, RS = 0.f;
#pragma unroll
    for (int j = 0; j < 8; ++j) {
        const float4 ca = cs4[2 * j];
        const float4 cb = cs4[2 * j + 1];
        const unsigned p0 = row[4 * j + 0];
        const unsigned p1 = row[4 * j + 1];
        const unsigned p2 = row[4 * j + 2];
        const unsigned p3 = row[4 * j + 3];
        P += bfl(p0) * ca.x + bfh(p0) * ca.y + bfl(p1) * ca.z + bfh(p1) * ca.w
           + bfl(p2) * cb.x + bfh(p2) * cb.y + bfl(p3) * cb.z + bfh(p3) * cb.w;
        RS += bfl(p0) + bfh(p0) + bfl(p1) + bfh(p1)
            + bfl(p2) + bfh(p2) + bfl(p3) + bfh(p3);
    }
    if (h == 1) { phalf[c][0] = P; phalf[c][1] = RS; }
    __syncthreads();
    if (t < C_) {
        P += phalf[t][0];
        RS += phalf[t][1];
        const size_t base = ((size_t)b * TPB_ + tile) * C_;
        Ppart [base + t] = P;
        RSpart[base + t] = RS;
    }
}

// ---------------------------------------------------------------------------
// kB: reduce 128 partials -> v -> fused MLP -> gate.  grid(B_) x 256.
// ---------------------------------------------------------------------------
__global__ void kB(const float* __restrict__ Ppart,
                   const float* __restrict__ RSpart,
                   const float* __restrict__ w1, const float* __restrict__ b1,
                   const float* __restrict__ w2, const float* __restrict__ b2,
                   float* __restrict__ gate) {
    const int b = blockIdx.x;
    const int t = threadIdx.x;   // channel c

    float P = 0.f, RS = 0.f;
#pragma unroll 8
    for (int k = 0; k < TPB_; ++k) {
        P  += Ppart [((size_t)b * TPB_ + k) * C_ + t];
        RS += RSpart[((size_t)b * TPB_ + k) * C_ + t];
    }

    __shared__ float red[4];
    float s = RS;
#pragma unroll
    for (int off = 32; off; off >>= 1) s += __shfl_down(s, off, 64);
    if ((t & 63) == 0) red[t >> 6] = s;
    __syncthreads();
    const float T = red[0] + red[1] + red[2] + red[3];
    const float M = T / (float)N_;
    const float denom = (float)(N_ - 1) * (float)C_;

    __shared__ float vl[C_];
    vl[t] = (P - M * RS) / denom;
    __syncthreads();

    __shared__ float hpart[R16_][16];
    __shared__ float h1[R16_];
    {
        const int i = t >> 4, cc = t & 15;
        float a = 0.f;
#pragma unroll
        for (int k = 0; k < 16; ++k)
            a += vl[(cc << 4) + k] * w1[i * C_ + (cc << 4) + k];
        hpart[i][cc] = a;
    }
    __syncthreads();
    if (t < R16_) {
        float a = b1[t];
#pragma unroll
        for (int k = 0; k < 16; ++k) a += hpart[t][k];
        h1[t] = a > 0.f ? a : 0.f;
    }
    __syncthreads();

    float a = b2[t];
#pragma unroll
    for (int i = 0; i < R16_; ++i) a += h1[i] * w2[t * R16_ + i];
    gate[b * C_ + t] = 1.f / (1.f + __expf(-a));
}

// ---------------------------------------------------------------------------
// kC: out = x * gate[b,c], REVERSE row order (boustrophedon vs kA's forward
// pass) so the x re-read starts at the L3's MRU end; nt stores keep x
// resident.  Next iteration's kA (forward) then starts where kC finished.
// ---------------------------------------------------------------------------
__global__ void kC(const float* __restrict__ x,
                   const float* __restrict__ gate,
                   float* __restrict__ out) {
    const int nrows = B_ * C_;           // 4096 rows of 4096 float4
    for (int row = blockIdx.x; row < nrows; row += gridDim.x) {
        const int rr = nrows - 1 - row;  // reverse traversal
        const float g = gate[rr];
        const float4* src = reinterpret_cast<const float4*>(x) + (size_t)rr * 4096;
        f32x4* dst = reinterpret_cast<f32x4*>(out) + (size_t)rr * 4096;
        for (int i = threadIdx.x; i < 4096; i += blockDim.x) {
            float4 vx = src[i];
            f32x4 r;
            r.x = vx.x * g; r.y = vx.y * g; r.z = vx.z * g; r.w = vx.w * g;
            __builtin_nontemporal_store(r, dst + i);
        }
    }
}

extern "C" void kernel_launch(void* const* d_in, const int* in_sizes, int n_in,
                              void* d_out, int out_size, void* d_ws, size_t ws_size,
                              hipStream_t stream) {
    (void)in_sizes; (void)n_in; (void)out_size; (void)ws_size;
    const float* x  = (const float*)d_in[0];
    const float* w1 = (const float*)d_in[1];
    const float* b1 = (const float*)d_in[2];
    const float* w2 = (const float*)d_in[3];
    const float* b2 = (const float*)d_in[4];
    float* out = (float*)d_out;

    float* ws     = (float*)d_ws;
    float* Ppart  = ws;                                    // B_*TPB_*C_ = 524288
    float* RSpart = Ppart + (size_t)B_ * TPB_ * C_;        // 524288
    float* gate   = RSpart + (size_t)B_ * TPB_ * C_;       // B_*C_

    hipLaunchKernelGGL(kA, dim3(TPB_, B_), dim3(512), 0, stream,
                       x, Ppart, RSpart);
    hipLaunchKernelGGL(kB, dim3(B_), dim3(256), 0, stream,
                       Ppart, RSpart, w1, b1, w2, b2, gate);
    hipLaunchKernelGGL(kC, dim3(2048), dim3(256), 0, stream,
                       x, gate, out);
}

// Round 15
// 138.452 us; speedup vs baseline: 1.6120x; 1.0120x over previous
//
#include <hip/hip_runtime.h>
#include <hip/hip_bf16.h>

#define B_ 16
#define C_ 256
#define N_ 16384      // 128*128
#define WT_ 256       // n per kA tile
#define TPB_ 64       // tiles per batch = N_/WT_
#define R16_ 16
#define TLSTR_ 129    // tile row stride in dwords (odd -> phase-B 2-way max)

typedef float f32x4 __attribute__((ext_vector_type(4)));

__device__ __forceinline__ float4 ldf4(const float* p) {
    return *reinterpret_cast<const float4*>(p);
}
__device__ __forceinline__ float bfl(unsigned p) {  // low bf16 -> f32
    return __uint_as_float(p << 16);
}
__device__ __forceinline__ float bfh(unsigned p) {  // high bf16 -> f32
    return __uint_as_float(p & 0xFFFF0000u);
}

// ---------------------------------------------------------------------------
// kA: fused stats pass, 1-KiB wave segments (fixes the 512B-burst ~4 TB/s cap
// of R13/R14).  1024 thr = 16 waves, tile = x[b, 0:256, n0:n0+256].
// Phase A: wave w streams rows 16w..16w+15, ONE float4/lane -> each load is a
// contiguous 1-KiB wave segment; colsum in f4 reg; values packed bf16
// (v_cvt_pk) into the dynamic-LDS tile (129-dword row stride).
// Phase B: thread t owns (c=t&255, quarter q=t>>8): 32 dword reads (2-way
// bank max) dotted against colsum; quarters combined via pq.
// LDS: 129 KiB dynamic tile + 23.5 KiB static -> 1 block/CU, 16 waves.
// P/RS from bf16 copy (R12-R14 proven: absmax unchanged vs fp32).
// ---------------------------------------------------------------------------
__global__ __launch_bounds__(1024)
void kA(const float* __restrict__ x,
        float* __restrict__ Ppart,
        float* __restrict__ RSpart) {
    extern __shared__ ushort tl[];          // [256][258] bf16, stride 129 dw
    __shared__ float4 csp[16][64];          // per-wave colsum partials
    __shared__ float colsum[WT_];
    __shared__ float2 pq[3][C_];            // phase-B quarter exchange

    const int tile = blockIdx.x;    // 0..63
    const int b = blockIdx.y;
    const int t = threadIdx.x;      // 0..1023
    const int lane = t & 63;
    const int w = t >> 6;           // wave 0..15

    const float* xt = x + (size_t)b * C_ * N_ + tile * WT_ + (lane << 2);
    const int c0 = w << 4;

    // ---- phase A: 16 contiguous 1-KiB wave loads, pack to bf16 tile
    float4 cs = make_float4(0.f, 0.f, 0.f, 0.f);
#pragma unroll
    for (int k = 0; k < 16; ++k) {
        const int c = c0 + k;
        float4 v = ldf4(xt + (size_t)c * N_);
        cs.x += v.x; cs.y += v.y; cs.z += v.z; cs.w += v.w;
        __hip_bfloat162 lo = __float22bfloat162_rn(make_float2(v.x, v.y));
        __hip_bfloat162 hi = __float22bfloat162_rn(make_float2(v.z, v.w));
        unsigned* dst = reinterpret_cast<unsigned*>(tl) + c * TLSTR_ + (lane << 1);
        dst[0] = *reinterpret_cast<unsigned*>(&lo);
        dst[1] = *reinterpret_cast<unsigned*>(&hi);
    }
    csp[w][lane] = cs;
    __syncthreads();

    // ---- colsum[n]: sum the 16 wave partials (t<256: n = t)
    if (t < WT_) {
        const float* base = reinterpret_cast<const float*>(&csp[0][t >> 2]) + (t & 3);
        float s = 0.f;
#pragma unroll
        for (int w2 = 0; w2 < 16; ++w2) s += base[w2 * 256];  // 64 f4 = 256 f
        colsum[t] = s;
    }
    __syncthreads();

    // ---- phase B: thread t owns (c = t&255, quarter q = t>>8)
    const int c = t & 255, q = t >> 8;
    const unsigned* row = reinterpret_cast<const unsigned*>(tl) + c * TLSTR_ + (q << 5);
    const float* csq = colsum + (q << 6);
    float P = 0.f, RS = 0.f;
#pragma unroll
    for (int j = 0; j < 32; ++j) {
        const unsigned pk = row[j];
        const float vx = bfl(pk), vy = bfh(pk);
        P += vx * csq[2 * j] + vy * csq[2 * j + 1];
        RS += vx + vy;
    }
    if (q) pq[q - 1][c] = make_float2(P, RS);
    __syncthreads();
    if (t < C_) {       // q == 0 threads finalize channel t
        P  += pq[0][t].x + pq[1][t].x + pq[2][t].x;
        RS += pq[0][t].y + pq[1][t].y + pq[2][t].y;
        const size_t base = ((size_t)b * TPB_ + tile) * C_;
        Ppart [base + t] = P;
        RSpart[base + t] = RS;
    }
}

// ---------------------------------------------------------------------------
// kB: reduce 64 partials -> v -> fused MLP -> gate.  grid(B_) x 256.
// ---------------------------------------------------------------------------
__global__ void kB(const float* __restrict__ Ppart,
                   const float* __restrict__ RSpart,
                   const float* __restrict__ w1, const float* __restrict__ b1,
                   const float* __restrict__ w2, const float* __restrict__ b2,
                   float* __restrict__ gate) {
    const int b = blockIdx.x;
    const int t = threadIdx.x;   // channel c

    float P = 0.f, RS = 0.f;
#pragma unroll 8
    for (int k = 0; k < TPB_; ++k) {
        P  += Ppart [((size_t)b * TPB_ + k) * C_ + t];
        RS += RSpart[((size_t)b * TPB_ + k) * C_ + t];
    }

    __shared__ float red[4];
    float s = RS;
#pragma unroll
    for (int off = 32; off; off >>= 1) s += __shfl_down(s, off, 64);
    if ((t & 63) == 0) red[t >> 6] = s;
    __syncthreads();
    const float T = red[0] + red[1] + red[2] + red[3];
    const float M = T / (float)N_;
    const float denom = (float)(N_ - 1) * (float)C_;

    __shared__ float vl[C_];
    vl[t] = (P - M * RS) / denom;
    __syncthreads();

    __shared__ float hpart[R16_][16];
    __shared__ float h1[R16_];
    {
        const int i = t >> 4, cc = t & 15;
        float a = 0.f;
#pragma unroll
        for (int k = 0; k < 16; ++k)
            a += vl[(cc << 4) + k] * w1[i * C_ + (cc << 4) + k];
        hpart[i][cc] = a;
    }
    __syncthreads();
    if (t < R16_) {
        float a = b1[t];
#pragma unroll
        for (int k = 0; k < 16; ++k) a += hpart[t][k];
        h1[t] = a > 0.f ? a : 0.f;
    }
    __syncthreads();

    float a = b2[t];
#pragma unroll
    for (int i = 0; i < R16_; ++i) a += h1[i] * w2[t * R16_ + i];
    gate[b * C_ + t] = 1.f / (1.f + __expf(-a));
}

// ---------------------------------------------------------------------------
// kC: out = x * gate[b,c], reverse traversal (boustrophedon) + nt stores.
// ---------------------------------------------------------------------------
__global__ void kC(const float* __restrict__ x,
                   const float* __restrict__ gate,
                   float* __restrict__ out) {
    const int nrows = B_ * C_;           // 4096 rows of 4096 float4
    for (int row = blockIdx.x; row < nrows; row += gridDim.x) {
        const int rr = nrows - 1 - row;  // reverse traversal
        const float g = gate[rr];
        const float4* src = reinterpret_cast<const float4*>(x) + (size_t)rr * 4096;
        f32x4* dst = reinterpret_cast<f32x4*>(out) + (size_t)rr * 4096;
        for (int i = threadIdx.x; i < 4096; i += blockDim.x) {
            float4 vx = src[i];
            f32x4 r;
            r.x = vx.x * g; r.y = vx.y * g; r.z = vx.z * g; r.w = vx.w * g;
            __builtin_nontemporal_store(r, dst + i);
        }
    }
}

extern "C" void kernel_launch(void* const* d_in, const int* in_sizes, int n_in,
                              void* d_out, int out_size, void* d_ws, size_t ws_size,
                              hipStream_t stream) {
    (void)in_sizes; (void)n_in; (void)out_size; (void)ws_size;
    const float* x  = (const float*)d_in[0];
    const float* w1 = (const float*)d_in[1];
    const float* b1 = (const float*)d_in[2];
    const float* w2 = (const float*)d_in[3];
    const float* b2 = (const float*)d_in[4];
    float* out = (float*)d_out;

    float* ws     = (float*)d_ws;
    float* Ppart  = ws;                                    // B_*TPB_*C_ = 262144
    float* RSpart = Ppart + (size_t)B_ * TPB_ * C_;        // 262144
    float* gate   = RSpart + (size_t)B_ * TPB_ * C_;       // B_*C_

    const int tl_bytes = C_ * (2 * TLSTR_) * (int)sizeof(ushort);  // 132096 B
    // allow >64 KiB dynamic LDS (host-side, idempotent, capture-safe)
    static bool attr_done = false;
    if (!attr_done) {
        hipFuncSetAttribute((const void*)kA,
                            hipFuncAttributeMaxDynamicSharedMemorySize,
                            tl_bytes);
        attr_done = true;
    }

    hipLaunchKernelGGL(kA, dim3(TPB_, B_), dim3(1024), tl_bytes, stream,
                       x, Ppart, RSpart);
    hipLaunchKernelGGL(kB, dim3(B_), dim3(256), 0, stream,
                       Ppart, RSpart, w1, b1, w2, b2, gate);
    hipLaunchKernelGGL(kC, dim3(2048), dim3(256), 0, stream,
                       x, gate, out);
}